// Round 20
// baseline (188.639 us; speedup 1.0000x reference)
//
#include <hip/hip_runtime.h>
#include <math.h>

#define T_TOTAL 16384   // B*S
#define C_DIM   4096
#define E_DIM   64
#define K_TOP   8
#define S_SEQ   4096
#define B_BATCH 4
#define NKQ     8       // K-eighths

typedef short  short8 __attribute__((ext_vector_type(8)));
typedef float  f32x4  __attribute__((ext_vector_type(4)));

__device__ __forceinline__ unsigned short bf16_rte(float x) {
    unsigned u = __float_as_uint(x);
    return (unsigned short)((u + 0x7fffu + ((u >> 16) & 1u)) >> 16);
}
__device__ __forceinline__ float bf16_back(unsigned short h) {
    return __uint_as_float(((unsigned)h) << 16);
}

// ---- pack W into B-fragment layout, 3 bf16 split planes (r13 verbatim) ----
// wb[((s*128 + kt)*4 + n)*64 + l] = uint4 of 8 bf16:
//   elem i = split_s( W[n*16 + (l&15)][kt*32 + (l>>4)*8 + i] )
__global__ void pack_w_kernel(const float* __restrict__ w,
                              uint4* __restrict__ wb) {
    int gidx = blockIdx.x * 256 + threadIdx.x;   // [0, 98304)
    int l  = gidx & 63;
    int n  = (gidx >> 6) & 3;
    int kt = (gidx >> 8) & 127;
    int s  = gidx >> 15;                         // 0..2
    int e  = n * 16 + (l & 15);
    int kb = kt * 32 + (l >> 4) * 8;
    const float* src = w + (size_t)e * C_DIM + kb;
    unsigned short h[8];
#pragma unroll
    for (int i = 0; i < 8; ++i) {
        float v = src[i];
        unsigned short b1 = bf16_rte(v);
        if (s == 0) { h[i] = b1; continue; }
        float r = v - bf16_back(b1);             // exact (Sterbenz)
        unsigned short b2 = bf16_rte(r);
        if (s == 1) { h[i] = b2; continue; }
        float r2 = r - bf16_back(b2);            // exact
        h[i] = bf16_rte(r2);
    }
    uint4 o;
    o.x = (unsigned)h[0] | ((unsigned)h[1] << 16);
    o.y = (unsigned)h[2] | ((unsigned)h[3] << 16);
    o.z = (unsigned)h[4] | ((unsigned)h[5] << 16);
    o.w = (unsigned)h[6] | ((unsigned)h[7] << 16);
    wb[gidx] = o;
}

__device__ __forceinline__ void split3(const float xv[8],
                                       short8& A1, short8& A2, short8& A3) {
#pragma unroll
    for (int i = 0; i < 8; ++i) {
        float v = xv[i];
        unsigned short h1 = bf16_rte(v);
        float r = v - bf16_back(h1);
        unsigned short h2 = bf16_rte(r);
        float r2 = r - bf16_back(h2);
        unsigned short h3 = bf16_rte(r2);
        A1[i] = (short)h1; A2[i] = (short)h2; A3[i] = (short)h3;
    }
}

// one K=32 step for TWO 16-row M-tiles sharing the same 12 B-frags (r15).
// Per-accumulator MFMA order identical to r13: A1B1,A1B2,A2B1,A1B3,A3B1,A2B2.
__device__ __forceinline__ void kstep2(const uint4* __restrict__ wstep,
                                       const float xa[8], const float xb[8],
                                       f32x4 accA[4], f32x4 accB[4]) {
    short8 a1, a2, a3, b1, b2, b3;
    split3(xa, a1, a2, a3);
    split3(xb, b1, b2, b3);
    uint4 q[3][4];
#pragma unroll
    for (int s = 0; s < 3; ++s)
#pragma unroll
        for (int n = 0; n < 4; ++n)
            q[s][n] = wstep[s * 32768 + n * 64];
    union { uint4 u; short8 v; } cv;
#pragma unroll
    for (int n = 0; n < 4; ++n) {
        short8 B1, B2, B3;
        cv.u = q[0][n]; B1 = cv.v;
        cv.u = q[1][n]; B2 = cv.v;
        cv.u = q[2][n]; B3 = cv.v;
        f32x4 cA = accA[n], cB = accB[n];
        cA = __builtin_amdgcn_mfma_f32_16x16x32_bf16(a1, B1, cA, 0, 0, 0);
        cB = __builtin_amdgcn_mfma_f32_16x16x32_bf16(b1, B1, cB, 0, 0, 0);
        cA = __builtin_amdgcn_mfma_f32_16x16x32_bf16(a1, B2, cA, 0, 0, 0);
        cB = __builtin_amdgcn_mfma_f32_16x16x32_bf16(b1, B2, cB, 0, 0, 0);
        cA = __builtin_amdgcn_mfma_f32_16x16x32_bf16(a2, B1, cA, 0, 0, 0);
        cB = __builtin_amdgcn_mfma_f32_16x16x32_bf16(b2, B1, cB, 0, 0, 0);
        cA = __builtin_amdgcn_mfma_f32_16x16x32_bf16(a1, B3, cA, 0, 0, 0);
        cB = __builtin_amdgcn_mfma_f32_16x16x32_bf16(b1, B3, cB, 0, 0, 0);
        cA = __builtin_amdgcn_mfma_f32_16x16x32_bf16(a3, B1, cA, 0, 0, 0);
        cB = __builtin_amdgcn_mfma_f32_16x16x32_bf16(b3, B1, cB, 0, 0, 0);
        cA = __builtin_amdgcn_mfma_f32_16x16x32_bf16(a2, B2, cA, 0, 0, 0);
        cB = __builtin_amdgcn_mfma_f32_16x16x32_bf16(b2, B2, cB, 0, 0, 0);
        accA[n] = cA; accB[n] = cB;
    }
}

#define XE(p, q) {p.x, p.y, p.z, p.w, q.x, q.y, q.z, q.w}

// ---- kernel 1: pure MFMA partial GEMM — no LDS, no barriers ----
// grid 1024 x 256 threads (4096 waves = 16 waves/CU). Wave = (32-token
// group tg = blk&511) x (K-eighth kq = (blk>>9)*4 + wv, 512 ch), M = 32
// (two 16-row tiles sharing B-frags — W traffic stays 786 MB). Partials
// to part[kq][tok][e]; kstep2 order, 256-ch flushes, pack and C/D map
// bit-identical to the r19 absmax=0 kernel.
__global__ __launch_bounds__(256, 2)
void gate_mfma_kernel(const float* __restrict__ x,
                      const uint4* __restrict__ wb,
                      float* __restrict__ part) {
    const int tid  = threadIdx.x;
    const int lane = tid & 63;
    const int kh   = tid >> 6;                   // 0..3
    const int tg   = blockIdx.x & 511;
    const int kq   = ((blockIdx.x >> 9) << 2) | kh;   // 0..7
    const int tok0 = tg * 32;
    const int row  = lane & 15;
    const int g    = lane >> 4;

    const float* xpa = x + (size_t)(tok0 + row) * C_DIM + kq * 512 + g * 8;
    const float* xpb = xpa + 16 * C_DIM;
    const uint4* wbl = wb + lane + (size_t)(kq * 16) * 256;  // + t*256

    f32x4 accIA[4], accOA[4], accIB[4], accOB[4];
#pragma unroll
    for (int n = 0; n < 4; ++n)
#pragma unroll
        for (int j = 0; j < 4; ++j) {
            accIA[n][j] = 0.0f; accOA[n][j] = 0.0f;
            accIB[n][j] = 0.0f; accOB[n][j] = 0.0f;
        }

    // 2-deep x prefetch per tile, named regs (even/odd)
    float4 eaA0 = *(const float4*)(xpa);
    float4 eaA1 = *(const float4*)(xpa + 4);
    float4 eaB0 = *(const float4*)(xpb);
    float4 eaB1 = *(const float4*)(xpb + 4);
    float4 obA0 = *(const float4*)(xpa + 32);
    float4 obA1 = *(const float4*)(xpa + 36);
    float4 obB0 = *(const float4*)(xpb + 32);
    float4 obB1 = *(const float4*)(xpb + 36);

#pragma unroll 1
    for (int t = 0; t < 16; t += 2) {
        {
            float xa[8] = XE(eaA0, eaA1);
            float xb[8] = XE(eaB0, eaB1);
            if (t + 2 < 16) {
                eaA0 = *(const float4*)(xpa + (t + 2) * 32);
                eaA1 = *(const float4*)(xpa + (t + 2) * 32 + 4);
                eaB0 = *(const float4*)(xpb + (t + 2) * 32);
                eaB1 = *(const float4*)(xpb + (t + 2) * 32 + 4);
            }
            kstep2(wbl + (size_t)t * 256, xa, xb, accIA, accIB);
        }
        {
            float xa[8] = XE(obA0, obA1);
            float xb[8] = XE(obB0, obB1);
            if (t + 3 < 16) {
                obA0 = *(const float4*)(xpa + (t + 3) * 32);
                obA1 = *(const float4*)(xpa + (t + 3) * 32 + 4);
                obB0 = *(const float4*)(xpb + (t + 3) * 32);
                obB1 = *(const float4*)(xpb + (t + 3) * 32 + 4);
            }
            kstep2(wbl + (size_t)(t + 1) * 256, xa, xb, accIA, accIB);
        }
        if ((t & 7) == 6) {                      // flush every 8 steps = 256 ch
#pragma unroll
            for (int n = 0; n < 4; ++n)
#pragma unroll
                for (int j = 0; j < 4; ++j) {
                    accOA[n][j] += accIA[n][j]; accIA[n][j] = 0.0f;
                    accOB[n][j] += accIB[n][j]; accIB[n][j] = 0.0f;
                }
        }
    }

    // store partials (r13 C/D map): part[kq][tok][expert]
    float* pb = part + (size_t)kq * T_TOTAL * E_DIM;
#pragma unroll
    for (int n = 0; n < 4; ++n)
#pragma unroll
        for (int r = 0; r < 4; ++r) {
            pb[(size_t)(tok0 + g * 4 + r) * E_DIM + n * 16 + row]      = accOA[n][r];
            pb[(size_t)(tok0 + 16 + g * 4 + r) * E_DIM + n * 16 + row] = accOB[n][r];
        }
}

// ---- kernel 2: reduce 8 eighths + sigmoid + top-8 (r8/r11-verified) ----
__global__ __launch_bounds__(256, 4)
void topk_kernel(const float* __restrict__ part,
                 const float* __restrict__ expert_bias,
                 float* __restrict__ out,
                 float* __restrict__ facc,
                 float* __restrict__ pacc) {
    const int lane = threadIdx.x & 63;
    const int wv   = threadIdx.x >> 6;
    const int tok0 = blockIdx.x * 64;

    __shared__ float slog[64][65];

    const int tt  = lane >> 2;
    const int s   = lane & 3;
    const int tl  = wv * 16 + tt;          // token-in-block
    const int tok = tok0 + tl;

    float4 sum4[4];
#pragma unroll
    for (int i = 0; i < 4; ++i) sum4[i] = make_float4(0.f, 0.f, 0.f, 0.f);
#pragma unroll
    for (int kq = 0; kq < NKQ; ++kq) {     // serial eighth sum (deterministic)
        const float4* pp = reinterpret_cast<const float4*>(
            part + ((size_t)kq * T_TOTAL + tok) * E_DIM + 16 * s);
#pragma unroll
        for (int i = 0; i < 4; ++i) {
            float4 v = pp[i];
            sum4[i].x += v.x; sum4[i].y += v.y;
            sum4[i].z += v.z; sum4[i].w += v.w;
        }
    }
#pragma unroll
    for (int i = 0; i < 4; ++i) {
        slog[tl][16 * s + 4 * i + 0] = sum4[i].x;
        slog[tl][16 * s + 4 * i + 1] = sum4[i].y;
        slog[tl][16 * s + 4 * i + 2] = sum4[i].z;
        slog[tl][16 * s + 4 * i + 3] = sum4[i].w;
    }
    __syncthreads();

    // ---- phase B: lane = expert; wave wv handles tokens wv*16 .. wv*16+15
    const float be = expert_bias[lane];
    const int   b  = tok0 / S_SEQ;         // uniform per block
    float f_local = 0.0f, p_local = 0.0f;

    for (int m = 0; m < 16; ++m) {
        const int tl2 = wv * 16 + m;
        const int tk  = tok0 + tl2;
        const float logit = slog[tl2][lane];
        const float sc = 1.0f / (1.0f + expf(-logit));   // sigmoid
        float ssum = sc;
#pragma unroll
        for (int off = 32; off >= 1; off >>= 1) ssum += __shfl_xor(ssum, off, 64);
        p_local += sc / (ssum + 1e-10f);

        // top-8 over biased logits (descending, lowest-index tie-break)
        float v = logit + be;
        float wsum = 0.0f, my_w = 0.0f;
        int   my_i = 0;
#pragma unroll
        for (int k = 0; k < K_TOP; ++k) {
            float rv = v;
            int   ri = lane;
#pragma unroll
            for (int off = 32; off >= 1; off >>= 1) {
                float ov = __shfl_xor(rv, off, 64);
                int   oi = __shfl_xor(ri, off, 64);
                if (ov > rv || (ov == rv && oi < ri)) { rv = ov; ri = oi; }
            }
            float wsc = __shfl(sc, ri, 64);   // winner's score (uniform)
            wsum += wsc;
            if (lane == k)  { my_i = ri; my_w = wsc; }
            if (lane == ri) { v = -INFINITY; f_local += 1.0f; }
        }
        if (lane < K_TOP) {
            out[(size_t)tk * K_TOP + lane] = (float)my_i;
            out[(size_t)T_TOTAL * K_TOP + (size_t)tk * K_TOP + lane] =
                my_w / (wsum + 1e-10f);
        }
    }

    atomicAdd(&facc[b * E_DIM + lane], f_local);
    atomicAdd(&pacc[b * E_DIM + lane], p_local);
}

// ---- tiny loss reduction: 4x64 f*p -> scalar ----
__global__ void loss_kernel(const float* __restrict__ facc,
                            const float* __restrict__ pacc,
                            float* __restrict__ out_loss) {
    const int tid = threadIdx.x;                 // 256 threads = B*E
    float f = facc[tid] * (1.0f / ((float)K_TOP * (float)S_SEQ));
    float p = pacc[tid] * (1.0f / (float)S_SEQ);
    float v = f * p;
#pragma unroll
    for (int off = 32; off >= 1; off >>= 1) v += __shfl_xor(v, off, 64);
    __shared__ float sred[4];
    if ((tid & 63) == 0) sred[tid >> 6] = v;
    __syncthreads();
    if (tid == 0) {
        float tot = sred[0] + sred[1] + sred[2] + sred[3];
        out_loss[0] = 0.001f * tot / (float)B_BATCH;
    }
}

extern "C" void kernel_launch(void* const* d_in, const int* in_sizes, int n_in,
                              void* d_out, int out_size, void* d_ws, size_t ws_size,
                              hipStream_t stream) {
    const float* x    = (const float*)d_in[0];   // [4,4096,4096] f32
    const float* w    = (const float*)d_in[1];   // [64,4096] f32
    const float* bias = (const float*)d_in[2];   // [64] f32
    float* out = (float*)d_out;                  // [131072 idx][131072 w][1 loss]

    float* facc = (float*)d_ws;                  // 256 floats
    float* pacc = facc + B_BATCH * E_DIM;        // 256 floats
    uint4* wb   = (uint4*)((char*)d_ws + 4096);  // 1.5 MB packed split-W
    float* part = (float*)((char*)d_ws + (2 << 20));   // 32 MB partials

    // zero the f/p accumulators every call (atomics accumulate)
    hipMemsetAsync(d_ws, 0, 2048, stream);

    pack_w_kernel<<<384, 256, 0, stream>>>(w, wb);

    gate_mfma_kernel<<<1024, 256, 0, stream>>>(x, wb, part);

    topk_kernel<<<T_TOTAL / 64, 256, 0, stream>>>(part, bias, out, facc, pacc);

    loss_kernel<<<1, 256, 0, stream>>>(facc, pacc, out + 2 * (size_t)T_TOTAL * K_TOP);
}

// Round 21
// 172.707 us; speedup vs baseline: 1.0922x; 1.0922x over previous
//
#include <hip/hip_runtime.h>
#include <math.h>

#define T_TOTAL 16384   // B*S
#define C_DIM   4096
#define E_DIM   64
#define K_TOP   8
#define S_SEQ   4096
#define B_BATCH 4
#define NKQ     8       // K-eighths
#define NT      16      // ksteps per block (512 ch / 32)

typedef short  short8 __attribute__((ext_vector_type(8)));
typedef float  f32x4  __attribute__((ext_vector_type(4)));

__device__ __forceinline__ unsigned short bf16_rte(float x) {
    unsigned u = __float_as_uint(x);
    return (unsigned short)((u + 0x7fffu + ((u >> 16) & 1u)) >> 16);
}
__device__ __forceinline__ float bf16_back(unsigned short h) {
    return __uint_as_float(((unsigned)h) << 16);
}

// ---- pack W into B-fragment layout, 3 bf16 split planes (r13 verbatim) ----
// wb[((s*128 + kt)*4 + n)*64 + l] = uint4 of 8 bf16:
//   elem i = split_s( W[n*16 + (l&15)][kt*32 + (l>>4)*8 + i] )
__global__ void pack_w_kernel(const float* __restrict__ w,
                              uint4* __restrict__ wb) {
    int gidx = blockIdx.x * 256 + threadIdx.x;   // [0, 98304)
    int l  = gidx & 63;
    int n  = (gidx >> 6) & 3;
    int kt = (gidx >> 8) & 127;
    int s  = gidx >> 15;                         // 0..2
    int e  = n * 16 + (l & 15);
    int kb = kt * 32 + (l >> 4) * 8;
    const float* src = w + (size_t)e * C_DIM + kb;
    unsigned short h[8];
#pragma unroll
    for (int i = 0; i < 8; ++i) {
        float v = src[i];
        unsigned short b1 = bf16_rte(v);
        if (s == 0) { h[i] = b1; continue; }
        float r = v - bf16_back(b1);             // exact (Sterbenz)
        unsigned short b2 = bf16_rte(r);
        if (s == 1) { h[i] = b2; continue; }
        float r2 = r - bf16_back(b2);            // exact
        h[i] = bf16_rte(r2);
    }
    uint4 o;
    o.x = (unsigned)h[0] | ((unsigned)h[1] << 16);
    o.y = (unsigned)h[2] | ((unsigned)h[3] << 16);
    o.z = (unsigned)h[4] | ((unsigned)h[5] << 16);
    o.w = (unsigned)h[6] | ((unsigned)h[7] << 16);
    wb[gidx] = o;
}

__device__ __forceinline__ void split3(const float xv[8],
                                       short8& A1, short8& A2, short8& A3) {
#pragma unroll
    for (int i = 0; i < 8; ++i) {
        float v = xv[i];
        unsigned short h1 = bf16_rte(v);
        float r = v - bf16_back(h1);
        unsigned short h2 = bf16_rte(r);
        float r2 = r - bf16_back(h2);
        unsigned short h3 = bf16_rte(r2);
        A1[i] = (short)h1; A2[i] = (short)h2; A3[i] = (short)h3;
    }
}

#define MFB(af, bf, acc) \
    acc = __builtin_amdgcn_mfma_f32_16x16x32_bf16(af, bf, acc, 0, 0, 0)

// ---- kernel 1: MFMA partial GEMM, W staged through LDS ----
// 512 blocks x 512 threads (8 waves): block = 256 tokens x 512-ch K-eighth
// (tg = blk&63, kq = blk>>6). Wave wv owns tokens [tg*256 + wv*32, +32) as
// two 16-row M-tiles sharing B-frags. Per kstep: all threads stage the
// 12 KB W-tile (global->reg early, reg->LDS late) into a 24 KB double
// buffer; waves consume via ds_read_b128 (latency covered by split3/MFMA).
// W global traffic 786 -> 96 MB (L2-hot). 1 barrier/kstep; 2 blocks/CU.
// Numerics: pack, split3, 6-term set {a1w1,a2w1,a3w1,a1w2,a2w2,a1w3}
// (plane-grouped order, same rounding class), k-map and C/D map identical
// to r13-r20 (absmax=0). Single-level acc: wave covers only 512 ch ->
// chain error sigma ~7e-6 (below the 1e-5 proven-safe line).
__global__ __launch_bounds__(512, 2)
void gate_mfma_kernel(const float* __restrict__ x,
                      const uint4* __restrict__ wb,
                      float* __restrict__ part) {
    const int tid  = threadIdx.x;
    const int lane = tid & 63;
    const int wv   = tid >> 6;          // 0..7
    const int tg   = blockIdx.x & 63;   // 256-token group
    const int kq   = blockIdx.x >> 6;   // 0..7: K-eighth
    const int tok0 = tg * 256;
    const int row  = lane & 15;
    const int g    = lane >> 4;
    const int wtok = tok0 + wv * 32;

    __shared__ uint4 wtile[2][768];     // 2 x 12 KB W tiles

    // staging map: chunk s0 = tid<256 -> wb[kt*256+tid]; s1 = tid in
    // [256,512) -> wb[32768+kt*256+tid-256]; s2 = tid<256 -> wb[65536+...].
    const uint4* wkt0 = wb + (size_t)(kq * NT) * 256;     // + t*256
    const int off0 = (tid < 256) ? tid : (32768 - 256 + tid);
    const int off1 = 65536 + tid;       // used when tid < 256

    const float* xpa = x + (size_t)(wtok + row) * C_DIM + kq * 512 + g * 8;
    const float* xpb = xpa + 16 * C_DIM;

    f32x4 accA[4], accB[4];
#pragma unroll
    for (int n = 0; n < 4; ++n)
#pragma unroll
        for (int j = 0; j < 4; ++j) { accA[n][j] = 0.0f; accB[n][j] = 0.0f; }

    // prologue: stage kstep 0 + load x for t=0
    {
        uint4 u0 = wkt0[off0];
        wtile[0][tid] = u0;
        if (tid < 256) {
            uint4 u1 = wkt0[off1];
            wtile[0][512 + tid] = u1;
        }
    }
    float4 xA0 = *(const float4*)(xpa);
    float4 xA1 = *(const float4*)(xpa + 4);
    float4 xB0 = *(const float4*)(xpb);
    float4 xB1 = *(const float4*)(xpb + 4);
    __syncthreads();

#pragma unroll 1
    for (int t = 0; t < NT; ++t) {
        const int cur = t & 1;
        const bool pf = (t + 1 < NT);

        // (1) issue W global prefetch for t+1 (in flight across compute)
        uint4 w0, w1;
        if (pf) {
            const uint4* wkt = wkt0 + (size_t)(t + 1) * 256;
            w0 = wkt[off0];
            if (tid < 256) w1 = wkt[off1];
        }

        // (2) split current x -> A-frags (covers plane-0 ds_read latency)
        const uint4* lp = &wtile[cur][lane];
        uint4 q00 = lp[0], q01 = lp[64], q02 = lp[128], q03 = lp[192];
        float xa[8] = {xA0.x, xA0.y, xA0.z, xA0.w, xA1.x, xA1.y, xA1.z, xA1.w};
        float xb[8] = {xB0.x, xB0.y, xB0.z, xB0.w, xB1.x, xB1.y, xB1.z, xB1.w};
        short8 a1, a2, a3, b1, b2, b3;
        split3(xa, a1, a2, a3);
        split3(xb, b1, b2, b3);

        // (3) reload x for t+1 (consumed next iteration; ~1 kstep in flight)
        if (pf) {
            xA0 = *(const float4*)(xpa + (t + 1) * 32);
            xA1 = *(const float4*)(xpa + (t + 1) * 32 + 4);
            xB0 = *(const float4*)(xpb + (t + 1) * 32);
            xB1 = *(const float4*)(xpb + (t + 1) * 32 + 4);
        }

        union { uint4 u; short8 v; } cv;
        // (4) plane 1 reads issued, then plane-0 MFMAs (cover the latency)
        uint4 q10 = lp[256], q11 = lp[320], q12 = lp[384], q13 = lp[448];
#pragma unroll
        for (int n = 0; n < 4; ++n) {
            cv.u = (n == 0) ? q00 : (n == 1) ? q01 : (n == 2) ? q02 : q03;
            const short8 B = cv.v;
            MFB(a1, B, accA[n]); MFB(b1, B, accB[n]);
            MFB(a2, B, accA[n]); MFB(b2, B, accB[n]);
            MFB(a3, B, accA[n]); MFB(b3, B, accB[n]);
        }
        uint4 q20 = lp[512], q21 = lp[576], q22 = lp[640], q23 = lp[704];
#pragma unroll
        for (int n = 0; n < 4; ++n) {
            cv.u = (n == 0) ? q10 : (n == 1) ? q11 : (n == 2) ? q12 : q13;
            const short8 B = cv.v;
            MFB(a1, B, accA[n]); MFB(b1, B, accB[n]);
            MFB(a2, B, accA[n]); MFB(b2, B, accB[n]);
        }
#pragma unroll
        for (int n = 0; n < 4; ++n) {
            cv.u = (n == 0) ? q20 : (n == 1) ? q21 : (n == 2) ? q22 : q23;
            const short8 B = cv.v;
            MFB(a1, B, accA[n]); MFB(b1, B, accB[n]);
        }

        // (5) commit W prefetch to the other buffer, then barrier
        if (pf) {
            wtile[cur ^ 1][tid] = w0;
            if (tid < 256) wtile[cur ^ 1][512 + tid] = w1;
        }
        __syncthreads();
    }

    // store partials (r13 C/D map): part[kq][tok][expert]
    float* pb = part + (size_t)kq * T_TOTAL * E_DIM;
#pragma unroll
    for (int n = 0; n < 4; ++n)
#pragma unroll
        for (int r = 0; r < 4; ++r) {
            pb[(size_t)(wtok + g * 4 + r) * E_DIM + n * 16 + row]      = accA[n][r];
            pb[(size_t)(wtok + 16 + g * 4 + r) * E_DIM + n * 16 + row] = accB[n][r];
        }
}

// ---- kernel 2: reduce 8 eighths + sigmoid + top-8 (r8/r11/r20-verified) ----
__global__ __launch_bounds__(256, 4)
void topk_kernel(const float* __restrict__ part,
                 const float* __restrict__ expert_bias,
                 float* __restrict__ out,
                 float* __restrict__ facc,
                 float* __restrict__ pacc) {
    const int lane = threadIdx.x & 63;
    const int wv   = threadIdx.x >> 6;
    const int tok0 = blockIdx.x * 64;

    __shared__ float slog[64][65];

    const int tt  = lane >> 2;
    const int s   = lane & 3;
    const int tl  = wv * 16 + tt;          // token-in-block
    const int tok = tok0 + tl;

    float4 sum4[4];
#pragma unroll
    for (int i = 0; i < 4; ++i) sum4[i] = make_float4(0.f, 0.f, 0.f, 0.f);
#pragma unroll
    for (int kq = 0; kq < NKQ; ++kq) {     // serial eighth sum (deterministic)
        const float4* pp = reinterpret_cast<const float4*>(
            part + ((size_t)kq * T_TOTAL + tok) * E_DIM + 16 * s);
#pragma unroll
        for (int i = 0; i < 4; ++i) {
            float4 v = pp[i];
            sum4[i].x += v.x; sum4[i].y += v.y;
            sum4[i].z += v.z; sum4[i].w += v.w;
        }
    }
#pragma unroll
    for (int i = 0; i < 4; ++i) {
        slog[tl][16 * s + 4 * i + 0] = sum4[i].x;
        slog[tl][16 * s + 4 * i + 1] = sum4[i].y;
        slog[tl][16 * s + 4 * i + 2] = sum4[i].z;
        slog[tl][16 * s + 4 * i + 3] = sum4[i].w;
    }
    __syncthreads();

    // ---- phase B: lane = expert; wave wv handles tokens wv*16 .. wv*16+15
    const float be = expert_bias[lane];
    const int   b  = tok0 / S_SEQ;         // uniform per block
    float f_local = 0.0f, p_local = 0.0f;

    for (int m = 0; m < 16; ++m) {
        const int tl2 = wv * 16 + m;
        const int tk  = tok0 + tl2;
        const float logit = slog[tl2][lane];
        const float sc = 1.0f / (1.0f + expf(-logit));   // sigmoid
        float ssum = sc;
#pragma unroll
        for (int off = 32; off >= 1; off >>= 1) ssum += __shfl_xor(ssum, off, 64);
        p_local += sc / (ssum + 1e-10f);

        // top-8 over biased logits (descending, lowest-index tie-break)
        float v = logit + be;
        float wsum = 0.0f, my_w = 0.0f;
        int   my_i = 0;
#pragma unroll
        for (int k = 0; k < K_TOP; ++k) {
            float rv = v;
            int   ri = lane;
#pragma unroll
            for (int off = 32; off >= 1; off >>= 1) {
                float ov = __shfl_xor(rv, off, 64);
                int   oi = __shfl_xor(ri, off, 64);
                if (ov > rv || (ov == rv && oi < ri)) { rv = ov; ri = oi; }
            }
            float wsc = __shfl(sc, ri, 64);   // winner's score (uniform)
            wsum += wsc;
            if (lane == k)  { my_i = ri; my_w = wsc; }
            if (lane == ri) { v = -INFINITY; f_local += 1.0f; }
        }
        if (lane < K_TOP) {
            out[(size_t)tk * K_TOP + lane] = (float)my_i;
            out[(size_t)T_TOTAL * K_TOP + (size_t)tk * K_TOP + lane] =
                my_w / (wsum + 1e-10f);
        }
    }

    atomicAdd(&facc[b * E_DIM + lane], f_local);
    atomicAdd(&pacc[b * E_DIM + lane], p_local);
}

// ---- tiny loss reduction: 4x64 f*p -> scalar ----
__global__ void loss_kernel(const float* __restrict__ facc,
                            const float* __restrict__ pacc,
                            float* __restrict__ out_loss) {
    const int tid = threadIdx.x;                 // 256 threads = B*E
    float f = facc[tid] * (1.0f / ((float)K_TOP * (float)S_SEQ));
    float p = pacc[tid] * (1.0f / (float)S_SEQ);
    float v = f * p;
#pragma unroll
    for (int off = 32; off >= 1; off >>= 1) v += __shfl_xor(v, off, 64);
    __shared__ float sred[4];
    if ((tid & 63) == 0) sred[tid >> 6] = v;
    __syncthreads();
    if (tid == 0) {
        float tot = sred[0] + sred[1] + sred[2] + sred[3];
        out_loss[0] = 0.001f * tot / (float)B_BATCH;
    }
}

extern "C" void kernel_launch(void* const* d_in, const int* in_sizes, int n_in,
                              void* d_out, int out_size, void* d_ws, size_t ws_size,
                              hipStream_t stream) {
    const float* x    = (const float*)d_in[0];   // [4,4096,4096] f32
    const float* w    = (const float*)d_in[1];   // [64,4096] f32
    const float* bias = (const float*)d_in[2];   // [64] f32
    float* out = (float*)d_out;                  // [131072 idx][131072 w][1 loss]

    float* facc = (float*)d_ws;                  // 256 floats
    float* pacc = facc + B_BATCH * E_DIM;        // 256 floats
    uint4* wb   = (uint4*)((char*)d_ws + 4096);  // 1.5 MB packed split-W
    float* part = (float*)((char*)d_ws + (2 << 20));   // 32 MB partials

    // zero the f/p accumulators every call (atomics accumulate)
    hipMemsetAsync(d_ws, 0, 2048, stream);

    pack_w_kernel<<<384, 256, 0, stream>>>(w, wb);

    gate_mfma_kernel<<<512, 512, 0, stream>>>(x, wb, part);

    topk_kernel<<<T_TOTAL / 64, 256, 0, stream>>>(part, bias, out, facc, pacc);

    loss_kernel<<<1, 256, 0, stream>>>(facc, pacc, out + 2 * (size_t)T_TOTAL * K_TOP);
}

// Round 22
// 135.255 us; speedup vs baseline: 1.3947x; 1.2769x over previous
//
#include <hip/hip_runtime.h>
#include <math.h>

#define T_TOTAL 16384   // B*S
#define C_DIM   4096
#define E_DIM   64
#define K_TOP   8
#define S_SEQ   4096
#define B_BATCH 4

typedef short  short8 __attribute__((ext_vector_type(8)));
typedef float  f32x4  __attribute__((ext_vector_type(4)));

__device__ __forceinline__ unsigned short bf16_rte(float x) {
    unsigned u = __float_as_uint(x);
    return (unsigned short)((u + 0x7fffu + ((u >> 16) & 1u)) >> 16);
}
__device__ __forceinline__ float bf16_back(unsigned short h) {
    return __uint_as_float(((unsigned)h) << 16);
}

// ---- pack W into B-fragment layout, 3 bf16 split planes (r13 verbatim) ----
// wb[((s*128 + kt)*4 + n)*64 + l] = uint4 of 8 bf16:
//   elem i = split_s( W[n*16 + (l&15)][kt*32 + (l>>4)*8 + i] )
__global__ void pack_w_kernel(const float* __restrict__ w,
                              uint4* __restrict__ wb) {
    int gidx = blockIdx.x * 256 + threadIdx.x;   // [0, 98304)
    int l  = gidx & 63;
    int n  = (gidx >> 6) & 3;
    int kt = (gidx >> 8) & 127;
    int s  = gidx >> 15;                         // 0..2
    int e  = n * 16 + (l & 15);
    int kb = kt * 32 + (l >> 4) * 8;
    const float* src = w + (size_t)e * C_DIM + kb;
    unsigned short h[8];
#pragma unroll
    for (int i = 0; i < 8; ++i) {
        float v = src[i];
        unsigned short b1 = bf16_rte(v);
        if (s == 0) { h[i] = b1; continue; }
        float r = v - bf16_back(b1);             // exact (Sterbenz)
        unsigned short b2 = bf16_rte(r);
        if (s == 1) { h[i] = b2; continue; }
        float r2 = r - bf16_back(b2);            // exact
        h[i] = bf16_rte(r2);
    }
    uint4 o;
    o.x = (unsigned)h[0] | ((unsigned)h[1] << 16);
    o.y = (unsigned)h[2] | ((unsigned)h[3] << 16);
    o.z = (unsigned)h[4] | ((unsigned)h[5] << 16);
    o.w = (unsigned)h[6] | ((unsigned)h[7] << 16);
    wb[gidx] = o;
}

__device__ __forceinline__ void split3(const float xv[8],
                                       short8& A1, short8& A2, short8& A3) {
#pragma unroll
    for (int i = 0; i < 8; ++i) {
        float v = xv[i];
        unsigned short h1 = bf16_rte(v);
        float r = v - bf16_back(h1);
        unsigned short h2 = bf16_rte(r);
        float r2 = r - bf16_back(h2);
        unsigned short h3 = bf16_rte(r2);
        A1[i] = (short)h1; A2[i] = (short)h2; A3[i] = (short)h3;
    }
}

// one K=32 step for TWO 16-row M-tiles sharing the same 12 B-frags.
// *** r22 change: the 12 W-fragment loads are issued FIRST, so their
// L2/L3 latency (~300-500 cyc) is covered by split3's ~600 cyc of
// independent VALU work. MFMA order per accumulator is bit-identical
// to r13-r21: A1B1,A1B2,A2B1,A1B3,A3B1,A2B2. ***
__device__ __forceinline__ void kstep2(const uint4* __restrict__ wstep,
                                       const float xa[8], const float xb[8],
                                       f32x4 accA[4], f32x4 accB[4]) {
    // (1) issue all W loads up front — in flight during split3
    uint4 q[3][4];
#pragma unroll
    for (int s = 0; s < 3; ++s)
#pragma unroll
        for (int n = 0; n < 4; ++n)
            q[s][n] = wstep[s * 32768 + n * 64];

    // (2) split x -> bf16x3 A-frags while W loads are in flight
    short8 a1, a2, a3, b1, b2, b3;
    split3(xa, a1, a2, a3);
    split3(xb, b1, b2, b3);

    // (3) MFMAs consume the (now-arrived) W fragments
    union { uint4 u; short8 v; } cv;
#pragma unroll
    for (int n = 0; n < 4; ++n) {
        short8 B1, B2, B3;
        cv.u = q[0][n]; B1 = cv.v;
        cv.u = q[1][n]; B2 = cv.v;
        cv.u = q[2][n]; B3 = cv.v;
        f32x4 cA = accA[n], cB = accB[n];
        cA = __builtin_amdgcn_mfma_f32_16x16x32_bf16(a1, B1, cA, 0, 0, 0);
        cB = __builtin_amdgcn_mfma_f32_16x16x32_bf16(b1, B1, cB, 0, 0, 0);
        cA = __builtin_amdgcn_mfma_f32_16x16x32_bf16(a1, B2, cA, 0, 0, 0);
        cB = __builtin_amdgcn_mfma_f32_16x16x32_bf16(b1, B2, cB, 0, 0, 0);
        cA = __builtin_amdgcn_mfma_f32_16x16x32_bf16(a2, B1, cA, 0, 0, 0);
        cB = __builtin_amdgcn_mfma_f32_16x16x32_bf16(b2, B1, cB, 0, 0, 0);
        cA = __builtin_amdgcn_mfma_f32_16x16x32_bf16(a1, B3, cA, 0, 0, 0);
        cB = __builtin_amdgcn_mfma_f32_16x16x32_bf16(b1, B3, cB, 0, 0, 0);
        cA = __builtin_amdgcn_mfma_f32_16x16x32_bf16(a3, B1, cA, 0, 0, 0);
        cB = __builtin_amdgcn_mfma_f32_16x16x32_bf16(b3, B1, cB, 0, 0, 0);
        cA = __builtin_amdgcn_mfma_f32_16x16x32_bf16(a2, B2, cA, 0, 0, 0);
        cB = __builtin_amdgcn_mfma_f32_16x16x32_bf16(b2, B2, cB, 0, 0, 0);
        accA[n] = cA; accB[n] = cB;
    }
}

#define XE(p, q) {p.x, p.y, p.z, p.w, q.x, q.y, q.z, q.w}

// ---- fused gate: bf16x3 MFMA GEMM (r19 base + W-loads-first kstep2) ----
// 512 blocks x 256 threads (4 waves). Block = 32 tokens; wave kh (0..3):
// 1024-ch K-quarter, M = 32 (two 16-row tiles sharing B-frags). slog = 32 KB.
// __launch_bounds__(256,2): the proven no-spill bound (r19: VGPR 96).
// Main loop, flushes, C/D map, epilogue bit-identical to r19 (absmax=0).
__global__ __launch_bounds__(256, 2)
void gate_mfma_kernel(const float* __restrict__ x,
                      const uint4* __restrict__ wb,
                      const float* __restrict__ expert_bias,
                      float* __restrict__ out,
                      float* __restrict__ facc,
                      float* __restrict__ pacc) {
    const int tid  = threadIdx.x;
    const int lane = tid & 63;
    const int kh   = tid >> 6;        // 0..3: K-quarter
    const int tok0 = blockIdx.x * 32;
    const int row  = lane & 15;
    const int g    = lane >> 4;

    __shared__ float slog[4][32][64];  // 32 KB

    const float* xpa = x + (size_t)(tok0 + row) * C_DIM + kh * 1024 + g * 8;
    const float* xpb = xpa + 16 * C_DIM;
    const uint4* wbl = wb + lane + (size_t)(kh * 32) * 256;  // + t*256

    f32x4 accIA[4], accOA[4], accIB[4], accOB[4];
#pragma unroll
    for (int n = 0; n < 4; ++n)
#pragma unroll
        for (int j = 0; j < 4; ++j) {
            accIA[n][j] = 0.0f; accOA[n][j] = 0.0f;
            accIB[n][j] = 0.0f; accOB[n][j] = 0.0f;
        }

    // 2-deep x prefetch per tile, named regs (even/odd)
    float4 eaA0 = *(const float4*)(xpa);
    float4 eaA1 = *(const float4*)(xpa + 4);
    float4 eaB0 = *(const float4*)(xpb);
    float4 eaB1 = *(const float4*)(xpb + 4);
    float4 obA0 = *(const float4*)(xpa + 32);
    float4 obA1 = *(const float4*)(xpa + 36);
    float4 obB0 = *(const float4*)(xpb + 32);
    float4 obB1 = *(const float4*)(xpb + 36);

#pragma unroll 1
    for (int t = 0; t < 32; t += 2) {
        {
            float xa[8] = XE(eaA0, eaA1);
            float xb[8] = XE(eaB0, eaB1);
            if (t + 2 < 32) {
                eaA0 = *(const float4*)(xpa + (t + 2) * 32);
                eaA1 = *(const float4*)(xpa + (t + 2) * 32 + 4);
                eaB0 = *(const float4*)(xpb + (t + 2) * 32);
                eaB1 = *(const float4*)(xpb + (t + 2) * 32 + 4);
            }
            kstep2(wbl + (size_t)t * 256, xa, xb, accIA, accIB);
        }
        {
            float xa[8] = XE(obA0, obA1);
            float xb[8] = XE(obB0, obB1);
            if (t + 3 < 32) {
                obA0 = *(const float4*)(xpa + (t + 3) * 32);
                obA1 = *(const float4*)(xpa + (t + 3) * 32 + 4);
                obB0 = *(const float4*)(xpb + (t + 3) * 32);
                obB1 = *(const float4*)(xpb + (t + 3) * 32 + 4);
            }
            kstep2(wbl + (size_t)(t + 1) * 256, xa, xb, accIA, accIB);
        }
        if ((t & 7) == 6) {                      // flush every 8 steps = 256 ch
#pragma unroll
            for (int n = 0; n < 4; ++n)
#pragma unroll
                for (int j = 0; j < 4; ++j) {
                    accOA[n][j] += accIA[n][j]; accIA[n][j] = 0.0f;
                    accOB[n][j] += accIB[n][j]; accIB[n][j] = 0.0f;
                }
        }
    }

    // write logits (r13 C/D map): slog[kh][token][expert]
#pragma unroll
    for (int n = 0; n < 4; ++n)
#pragma unroll
        for (int r = 0; r < 4; ++r) {
            slog[kh][g * 4 + r][n * 16 + row]      = accOA[n][r];
            slog[kh][16 + g * 4 + r][n * 16 + row] = accOB[n][r];
        }
    __syncthreads();

    // ---- phase 2: verified top-8 butterfly; wave kh handles 8 tokens ----
    const float be = expert_bias[lane];
    const int   b  = tok0 / S_SEQ;               // uniform per block
    float f_local = 0.0f, p_local = 0.0f;

    for (int m = 0; m < 8; ++m) {
        const int tl = kh * 8 + m;
        const int tk = tok0 + tl;
        const float logit = slog[0][tl][lane] + slog[1][tl][lane]
                          + slog[2][tl][lane] + slog[3][tl][lane];
        const float sc = 1.0f / (1.0f + expf(-logit));   // sigmoid
        float ssum = sc;
#pragma unroll
        for (int off = 32; off >= 1; off >>= 1) ssum += __shfl_xor(ssum, off, 64);
        p_local += sc / (ssum + 1e-10f);

        float v = logit + be;
        float wsum = 0.0f, my_w = 0.0f;
        int   my_i = 0;
#pragma unroll
        for (int k = 0; k < K_TOP; ++k) {
            float rv = v;
            int   ri = lane;
#pragma unroll
            for (int off = 32; off >= 1; off >>= 1) {
                float ov = __shfl_xor(rv, off, 64);
                int   oi = __shfl_xor(ri, off, 64);
                if (ov > rv || (ov == rv && oi < ri)) { rv = ov; ri = oi; }
            }
            float wsc = __shfl(sc, ri, 64);      // winner's score (uniform)
            wsum += wsc;
            if (lane == k)  { my_i = ri; my_w = wsc; }
            if (lane == ri) { v = -INFINITY; f_local += 1.0f; }
        }
        if (lane < K_TOP) {
            out[(size_t)tk * K_TOP + lane] = (float)my_i;
            out[(size_t)T_TOTAL * K_TOP + (size_t)tk * K_TOP + lane] =
                my_w / (wsum + 1e-10f);
        }
    }

    atomicAdd(&facc[b * E_DIM + lane], f_local);
    atomicAdd(&pacc[b * E_DIM + lane], p_local);
}

// ---- tiny loss reduction: 4x64 f*p -> scalar ----
__global__ void loss_kernel(const float* __restrict__ facc,
                            const float* __restrict__ pacc,
                            float* __restrict__ out_loss) {
    const int tid = threadIdx.x;                 // 256 threads = B*E
    float f = facc[tid] * (1.0f / ((float)K_TOP * (float)S_SEQ));
    float p = pacc[tid] * (1.0f / (float)S_SEQ);
    float v = f * p;
#pragma unroll
    for (int off = 32; off >= 1; off >>= 1) v += __shfl_xor(v, off, 64);
    __shared__ float sred[4];
    if ((tid & 63) == 0) sred[tid >> 6] = v;
    __syncthreads();
    if (tid == 0) {
        float tot = sred[0] + sred[1] + sred[2] + sred[3];
        out_loss[0] = 0.001f * tot / (float)B_BATCH;
    }
}

extern "C" void kernel_launch(void* const* d_in, const int* in_sizes, int n_in,
                              void* d_out, int out_size, void* d_ws, size_t ws_size,
                              hipStream_t stream) {
    const float* x    = (const float*)d_in[0];   // [4,4096,4096] f32
    const float* w    = (const float*)d_in[1];   // [64,4096] f32
    const float* bias = (const float*)d_in[2];   // [64] f32
    float* out = (float*)d_out;                  // [131072 idx][131072 w][1 loss]

    float* facc = (float*)d_ws;                  // 256 floats
    float* pacc = facc + B_BATCH * E_DIM;        // 256 floats
    uint4* wb   = (uint4*)((char*)d_ws + 4096);  // 1.5 MB packed split-W

    // zero the f/p accumulators every call (atomics accumulate)
    hipMemsetAsync(d_ws, 0, 2048, stream);

    pack_w_kernel<<<384, 256, 0, stream>>>(w, wb);

    gate_mfma_kernel<<<512, 256, 0, stream>>>(x, wb, bias, out, facc, pacc);

    loss_kernel<<<1, 256, 0, stream>>>(facc, pacc, out + 2 * (size_t)T_TOTAL * K_TOP);
}

// Round 23
// 115.163 us; speedup vs baseline: 1.6380x; 1.1745x over previous
//
#include <hip/hip_runtime.h>
#include <math.h>

#define T_TOTAL 16384   // B*S
#define C_DIM   4096
#define E_DIM   64
#define K_TOP   8
#define S_SEQ   4096
#define B_BATCH 4

typedef short  short8 __attribute__((ext_vector_type(8)));
typedef float  f32x4  __attribute__((ext_vector_type(4)));

__device__ __forceinline__ unsigned short bf16_rte(float x) {
    unsigned u = __float_as_uint(x);
    return (unsigned short)((u + 0x7fffu + ((u >> 16) & 1u)) >> 16);
}
__device__ __forceinline__ float bf16_back(unsigned short h) {
    return __uint_as_float(((unsigned)h) << 16);
}

// ---- pack W into B-fragment layout, 3 bf16 split planes (r13 verbatim) ----
// wb[((s*128 + kt)*4 + n)*64 + l] = uint4 of 8 bf16:
//   elem i = split_s( W[n*16 + (l&15)][kt*32 + (l>>4)*8 + i] )
__global__ void pack_w_kernel(const float* __restrict__ w,
                              uint4* __restrict__ wb) {
    int gidx = blockIdx.x * 256 + threadIdx.x;   // [0, 98304)
    int l  = gidx & 63;
    int n  = (gidx >> 6) & 3;
    int kt = (gidx >> 8) & 127;
    int s  = gidx >> 15;                         // 0..2
    int e  = n * 16 + (l & 15);
    int kb = kt * 32 + (l >> 4) * 8;
    const float* src = w + (size_t)e * C_DIM + kb;
    unsigned short h[8];
#pragma unroll
    for (int i = 0; i < 8; ++i) {
        float v = src[i];
        unsigned short b1 = bf16_rte(v);
        if (s == 0) { h[i] = b1; continue; }
        float r = v - bf16_back(b1);             // exact (Sterbenz)
        unsigned short b2 = bf16_rte(r);
        if (s == 1) { h[i] = b2; continue; }
        float r2 = r - bf16_back(b2);            // exact
        h[i] = bf16_rte(r2);
    }
    uint4 o;
    o.x = (unsigned)h[0] | ((unsigned)h[1] << 16);
    o.y = (unsigned)h[2] | ((unsigned)h[3] << 16);
    o.z = (unsigned)h[4] | ((unsigned)h[5] << 16);
    o.w = (unsigned)h[6] | ((unsigned)h[7] << 16);
    wb[gidx] = o;
}

__device__ __forceinline__ void split3(const float xv[8],
                                       short8& A1, short8& A2, short8& A3) {
#pragma unroll
    for (int i = 0; i < 8; ++i) {
        float v = xv[i];
        unsigned short h1 = bf16_rte(v);
        float r = v - bf16_back(h1);
        unsigned short h2 = bf16_rte(r);
        float r2 = r - bf16_back(h2);
        unsigned short h3 = bf16_rte(r2);
        A1[i] = (short)h1; A2[i] = (short)h2; A3[i] = (short)h3;
    }
}

#define MFB(af, bf, acc) \
    acc = __builtin_amdgcn_mfma_f32_16x16x32_bf16(af, bf, acc, 0, 0, 0)

#define SPLIT_TILE(m, P0, P1)                                            \
    {                                                                    \
        float xv_[8] = {P0.x, P0.y, P0.z, P0.w, P1.x, P1.y, P1.z, P1.w};\
        split3(xv_, a1[m], a2[m], a3[m]);                                \
    }

// ---- fused gate: bf16x3 MFMA GEMM, M=64/wave (4 tiles share B-frags) ----
// 256 blocks x 512 threads (8 waves) = 1 block/CU, 8 waves/CU. Block = 64
// tokens; wave kq (0..7): 512-ch K-eighth, M = 64 as four 16-row tiles
// sharing the same 12 B-frags -> 12 W loads feed 48 MFMAs (W instrs and
// W traffic halved vs r19; total VMEM instrs -38%). Single-level acc per
// 512-ch chain (r21 precedent, absmax=0). kstep MFMA order per accumulator,
// split3, pack, k-map, C/D map bit-identical to r13-r22. Two-stage slog
// reduction: kq<4 write planes, barrier, kq>=4 add, barrier, 4-plane
// ascending epilogue (verified butterfly).
__global__ __launch_bounds__(512, 2)
void gate_mfma_kernel(const float* __restrict__ x,
                      const uint4* __restrict__ wb,
                      const float* __restrict__ expert_bias,
                      float* __restrict__ out,
                      float* __restrict__ facc,
                      float* __restrict__ pacc) {
    const int tid  = threadIdx.x;
    const int lane = tid & 63;
    const int kq   = tid >> 6;        // 0..7: K-eighth
    const int tok0 = blockIdx.x * 64;
    const int row  = lane & 15;
    const int g    = lane >> 4;

    __shared__ float slog[4][64][64]; // 64 KB

    const float* xp0 = x + (size_t)(tok0 + row) * C_DIM + kq * 512 + g * 8;
    const float* xp1 = xp0 + 16 * C_DIM;
    const float* xp2 = xp0 + 32 * C_DIM;
    const float* xp3 = xp0 + 48 * C_DIM;
    const uint4* wbl = wb + lane + (size_t)(kq * 16) * 256;  // + t*256

    f32x4 acc[4][4];                  // [tile][n]
#pragma unroll
    for (int m = 0; m < 4; ++m)
#pragma unroll
        for (int n = 0; n < 4; ++n)
#pragma unroll
            for (int j = 0; j < 4; ++j) acc[m][n][j] = 0.0f;

    // 1-deep x prefetch: 8 named float4 (2 per tile)
    float4 cA0 = *(const float4*)(xp0);
    float4 cA1 = *(const float4*)(xp0 + 4);
    float4 cB0 = *(const float4*)(xp1);
    float4 cB1 = *(const float4*)(xp1 + 4);
    float4 cC0 = *(const float4*)(xp2);
    float4 cC1 = *(const float4*)(xp2 + 4);
    float4 cD0 = *(const float4*)(xp3);
    float4 cD1 = *(const float4*)(xp3 + 4);

#pragma unroll 1
    for (int t = 0; t < 16; ++t) {
        // (1) issue the 12 shared W loads
        const uint4* wstep = wbl + (size_t)t * 256;
        uint4 q0[4], q1[4], q2[4];
#pragma unroll
        for (int n = 0; n < 4; ++n) {
            q0[n] = wstep[n * 64];
            q1[n] = wstep[32768 + n * 64];
            q2[n] = wstep[65536 + n * 64];
        }

        // (2) split the 4 tiles' x (covers W latency with VALU)
        short8 a1[4], a2[4], a3[4];
        SPLIT_TILE(0, cA0, cA1)
        SPLIT_TILE(1, cB0, cB1)
        SPLIT_TILE(2, cC0, cC1)
        SPLIT_TILE(3, cD0, cD1)

        // (3) reload prefetch regs for t+1 (in flight across the MFMAs)
        if (t + 1 < 16) {
            const int o = (t + 1) * 32;
            cA0 = *(const float4*)(xp0 + o); cA1 = *(const float4*)(xp0 + o + 4);
            cB0 = *(const float4*)(xp1 + o); cB1 = *(const float4*)(xp1 + o + 4);
            cC0 = *(const float4*)(xp2 + o); cC1 = *(const float4*)(xp2 + o + 4);
            cD0 = *(const float4*)(xp3 + o); cD1 = *(const float4*)(xp3 + o + 4);
        }

        // (4) 48 MFMAs: per accumulator the canonical 6-product order
        union { uint4 u; short8 v; } cv;
#pragma unroll
        for (int n = 0; n < 4; ++n) {
            cv.u = q0[n]; const short8 B1 = cv.v;
            cv.u = q1[n]; const short8 B2 = cv.v;
            cv.u = q2[n]; const short8 B3 = cv.v;
#pragma unroll
            for (int m = 0; m < 4; ++m) {
                f32x4 c = acc[m][n];
                MFB(a1[m], B1, c);
                MFB(a1[m], B2, c);
                MFB(a2[m], B1, c);
                MFB(a1[m], B3, c);
                MFB(a3[m], B1, c);
                MFB(a2[m], B2, c);
                acc[m][n] = c;
            }
        }
    }

    // ---- two-stage slog reduction (race-free via barriers) ----
    if (kq < 4) {
#pragma unroll
        for (int m = 0; m < 4; ++m)
#pragma unroll
            for (int n = 0; n < 4; ++n)
#pragma unroll
                for (int r = 0; r < 4; ++r)
                    slog[kq][m * 16 + g * 4 + r][n * 16 + row] = acc[m][n][r];
    }
    __syncthreads();
    if (kq >= 4) {
        const int p = kq - 4;
#pragma unroll
        for (int m = 0; m < 4; ++m)
#pragma unroll
            for (int n = 0; n < 4; ++n)
#pragma unroll
                for (int r = 0; r < 4; ++r)
                    slog[p][m * 16 + g * 4 + r][n * 16 + row] += acc[m][n][r];
    }
    __syncthreads();

    // ---- phase 2: verified top-8 butterfly; wave kq handles 8 tokens ----
    const float be = expert_bias[lane];
    const int   b  = tok0 / S_SEQ;               // uniform per block
    float f_local = 0.0f, p_local = 0.0f;

    for (int m = 0; m < 8; ++m) {
        const int tl = kq * 8 + m;
        const int tk = tok0 + tl;
        const float logit = slog[0][tl][lane] + slog[1][tl][lane]
                          + slog[2][tl][lane] + slog[3][tl][lane];
        const float sc = 1.0f / (1.0f + expf(-logit));   // sigmoid
        float ssum = sc;
#pragma unroll
        for (int off = 32; off >= 1; off >>= 1) ssum += __shfl_xor(ssum, off, 64);
        p_local += sc / (ssum + 1e-10f);

        float v = logit + be;
        float wsum = 0.0f, my_w = 0.0f;
        int   my_i = 0;
#pragma unroll
        for (int k = 0; k < K_TOP; ++k) {
            float rv = v;
            int   ri = lane;
#pragma unroll
            for (int off = 32; off >= 1; off >>= 1) {
                float ov = __shfl_xor(rv, off, 64);
                int   oi = __shfl_xor(ri, off, 64);
                if (ov > rv || (ov == rv && oi < ri)) { rv = ov; ri = oi; }
            }
            float wsc = __shfl(sc, ri, 64);      // winner's score (uniform)
            wsum += wsc;
            if (lane == k)  { my_i = ri; my_w = wsc; }
            if (lane == ri) { v = -INFINITY; f_local += 1.0f; }
        }
        if (lane < K_TOP) {
            out[(size_t)tk * K_TOP + lane] = (float)my_i;
            out[(size_t)T_TOTAL * K_TOP + (size_t)tk * K_TOP + lane] =
                my_w / (wsum + 1e-10f);
        }
    }

    atomicAdd(&facc[b * E_DIM + lane], f_local);
    atomicAdd(&pacc[b * E_DIM + lane], p_local);
}

// ---- tiny loss reduction: 4x64 f*p -> scalar ----
__global__ void loss_kernel(const float* __restrict__ facc,
                            const float* __restrict__ pacc,
                            float* __restrict__ out_loss) {
    const int tid = threadIdx.x;                 // 256 threads = B*E
    float f = facc[tid] * (1.0f / ((float)K_TOP * (float)S_SEQ));
    float p = pacc[tid] * (1.0f / (float)S_SEQ);
    float v = f * p;
#pragma unroll
    for (int off = 32; off >= 1; off >>= 1) v += __shfl_xor(v, off, 64);
    __shared__ float sred[4];
    if ((tid & 63) == 0) sred[tid >> 6] = v;
    __syncthreads();
    if (tid == 0) {
        float tot = sred[0] + sred[1] + sred[2] + sred[3];
        out_loss[0] = 0.001f * tot / (float)B_BATCH;
    }
}

extern "C" void kernel_launch(void* const* d_in, const int* in_sizes, int n_in,
                              void* d_out, int out_size, void* d_ws, size_t ws_size,
                              hipStream_t stream) {
    const float* x    = (const float*)d_in[0];   // [4,4096,4096] f32
    const float* w    = (const float*)d_in[1];   // [64,4096] f32
    const float* bias = (const float*)d_in[2];   // [64] f32
    float* out = (float*)d_out;                  // [131072 idx][131072 w][1 loss]

    float* facc = (float*)d_ws;                  // 256 floats
    float* pacc = facc + B_BATCH * E_DIM;        // 256 floats
    uint4* wb   = (uint4*)((char*)d_ws + 4096);  // 1.5 MB packed split-W

    // zero the f/p accumulators every call (atomics accumulate)
    hipMemsetAsync(d_ws, 0, 2048, stream);

    pack_w_kernel<<<384, 256, 0, stream>>>(w, wb);

    gate_mfma_kernel<<<256, 512, 0, stream>>>(x, wb, bias, out, facc, pacc);

    loss_kernel<<<1, 256, 0, stream>>>(facc, pacc, out + 2 * (size_t)T_TOTAL * K_TOP);
}